// Round 19
// baseline (139.130 us; speedup 1.0000x reference)
//
#include <hip/hip_runtime.h>
#include <hip/hip_fp16.h>
#include <stdint.h>

#define N_NODES 100000
#define N_EDGES 1000000
#define DIM 64
#define MAXD 32                  // ELL width: 128B index row per node
#define SENT N_NODES             // sentinel -> zero row in v-buffers
#define BKT_SHIFT 7
#define BKT_NODES 128            // nodes per bucket
#define NBKT ((N_NODES + BKT_NODES - 1) / BKT_NODES)   // 782
#define BKT_CAP 2048             // >>20 sigma above mean 1279 edges/bucket
#define OVF_CAP 16384
#define CHUNK 4096               // edges per scatter block (245 blocks)
#define NCHUNK ((N_EDGES + CHUNK - 1) / CHUNK)
#define CURS_STRIDE 16
#define LROWS 64                 // linear: rows per block

__device__ __forceinline__ int load_src(const void* edges, int is64, int e) {
    if (is64) return ((const int2*)edges)[e].x;            // int64 values < 2^31
    return ((const int*)edges)[e];
}
__device__ __forceinline__ int load_dst(const void* edges, int is64, int e) {
    if (is64) return ((const int2*)edges)[N_EDGES + e].x;
    return ((const int*)edges)[N_EDGES + e];
}
__device__ __forceinline__ int detect64(const void* edges) {
    const long long* e64 = (const long long*)edges;
    int is64 = 1;
#pragma unroll
    for (int k = 0; k < 8; ++k) {
        long long v = e64[k];
        if (v < 0 || v >= (long long)N_NODES) is64 = 0;
    }
    return is64;
}

// pass A: per-block bucket histogram -> hist[blk][b]. Also zeroes cnt/ovf_cnt,
// publishes flag, and zeroes the SENT rows of the three v-buffers (block 0).
__global__ __launch_bounds__(256) void hist_kernel(const void* __restrict__ edges,
                                                   int* __restrict__ flag,
                                                   int* __restrict__ cnt,
                                                   int* __restrict__ ovf_cnt,
                                                   int* __restrict__ hist,
                                                   __half* __restrict__ xh,
                                                   __half* __restrict__ bA,
                                                   __half* __restrict__ bB) {
    __shared__ int lcnt[NBKT];
    int t = threadIdx.x;
    int is64 = detect64(edges);                 // block-local, identical result
    if (blockIdx.x == 0) {
        if (t == 0) { *flag = is64; *ovf_cnt = 0; }
        if (t < 96) {                           // zero SENT rows (3 bufs x 32 half2)
            int r = t >> 5, c = t & 31;
            __half* bufs[3] = {xh, bA, bB};
            ((__half2*)(bufs[r] + (size_t)SENT * DIM))[c] = __floats2half2_rn(0.f, 0.f);
        }
    }
    for (int i = blockIdx.x * 256 + t; i < N_NODES; i += NCHUNK * 256)
        cnt[i] = 0;
    int e0 = blockIdx.x * CHUNK;
    int e1 = min(e0 + CHUNK, N_EDGES);
    for (int i = t; i < NBKT; i += 256) lcnt[i] = 0;
    __syncthreads();
    for (int e = e0 + t; e < e1; e += 256)
        atomicAdd(&lcnt[load_dst(edges, is64, e) >> BKT_SHIFT], 1);
    __syncthreads();
    int* row = hist + (size_t)blockIdx.x * NBKT;
    for (int i = t; i < NBKT; i += 256) row[i] = lcnt[i];   // coalesced
}

// pass B: one wave per bucket: exclusive prefix over NCHUNK blocks, in place.
__global__ __launch_bounds__(256) void scan_kernel(int* __restrict__ hist,
                                                   int* __restrict__ cursors) {
    int b = blockIdx.x * 4 + (threadIdx.x >> 6);
    if (b >= NBKT) return;
    int lane = threadIdx.x & 63;
    int carry = 0;
    for (int r0 = 0; r0 < NCHUNK; r0 += 64) {
        int r = r0 + lane;
        int v = (r < NCHUNK) ? hist[(size_t)r * NBKT + b] : 0;
        int incl = v;
#pragma unroll
        for (int off = 1; off < 64; off <<= 1) {
            int u = __shfl_up(incl, off, 64);
            if (lane >= off) incl += u;
        }
        if (r < NCHUNK) hist[(size_t)r * NBKT + b] = incl - v + carry;  // exclusive
        carry += __shfl(incl, 63, 64);
    }
    if (lane == 0) cursors[b * CURS_STRIDE] = carry;        // total count
}

// pass C: scatter with LDS cursors only (no global atomics).
__global__ __launch_bounds__(256) void scatter2(const void* __restrict__ edges,
                                                const int* __restrict__ flag,
                                                const int* __restrict__ hist,
                                                int* __restrict__ cnt,
                                                int* __restrict__ buckets,
                                                int2* __restrict__ ovf,
                                                int* __restrict__ ovf_cnt) {
    __shared__ int lbase[NBKT];
    __shared__ int lcur[NBKT];
    int t = threadIdx.x;
    int e0 = blockIdx.x * CHUNK;
    int e1 = min(e0 + CHUNK, N_EDGES);
    int is64 = *flag;
    const int* row = hist + (size_t)blockIdx.x * NBKT;
    for (int i = t; i < NBKT; i += 256) { lbase[i] = row[i]; lcur[i] = 0; }
    __syncthreads();
    for (int e = e0 + t; e < e1; e += 256) {
        int s = load_src(edges, is64, e);
        int d = load_dst(edges, is64, e);
        int b = d >> BKT_SHIFT;
        int pos = lbase[b] + atomicAdd(&lcur[b], 1);        // global pos in bucket
        if (pos < BKT_CAP) {
            buckets[(size_t)b * BKT_CAP + pos] = s | ((d & (BKT_NODES - 1)) << 17);
        } else {                                            // astronomically rare
            atomicAdd(&cnt[d], 1);
            int o = atomicAdd(ovf_cnt, 1);
            if (o < OVF_CAP) ovf[o] = make_int2(s, d);
        }
    }
}

// per-bucket ELL build + fused vinit: LDS degree counters -> cnt/ellcnt/dinv,
// pair-max SENT padding, then this block converts ITS OWN 128 x-rows to fp16
// v-space (xh = fp16(dinv*x)).
__global__ __launch_bounds__(256) void ell_build(const int* __restrict__ cursors,
                                                 int* __restrict__ cnt,
                                                 int* __restrict__ ellcnt,
                                                 float* __restrict__ dinv,
                                                 const int* __restrict__ buckets,
                                                 int* __restrict__ ell,
                                                 int2* __restrict__ ovf,
                                                 int* __restrict__ ovf_cnt,
                                                 const float* __restrict__ x,
                                                 __half* __restrict__ xh) {
    __shared__ int lcnt[BKT_NODES];
    __shared__ float sdinv[BKT_NODES];
    int b = blockIdx.x, t = threadIdx.x;
    if (t < BKT_NODES) lcnt[t] = 0;
    __syncthreads();
    int m = cursors[b * CURS_STRIDE];
    if (m > BKT_CAP) m = BKT_CAP;
    int base = b * BKT_NODES;
    const int* be = buckets + (size_t)b * BKT_CAP;
    for (int i = t; i < m; i += 256) {
        int pe = be[i];
        int s = pe & 0x1FFFF;
        int off = pe >> 17;
        int k = atomicAdd(&lcnt[off], 1);
        if (k < MAXD) ell[(size_t)(base + off) * MAXD + k] = s;
        else {
            int o = atomicAdd(ovf_cnt, 1);
            if (o < OVF_CAP) ovf[o] = make_int2(s, base + off);
        }
    }
    __syncthreads();
    if (t < BKT_NODES) {
        int g = base + t;
        if (g < N_NODES) {
            int tot = cnt[g] + lcnt[t];
            cnt[g] = tot;
            int ec = lcnt[t] < MAXD ? lcnt[t] : MAXD;
            ellcnt[g] = ec;
            float dv = rsqrtf((float)(tot + 1));
            dinv[g] = dv;
            sdinv[t] = dv;
            int ecn = lcnt[t ^ 1] < MAXD ? lcnt[t ^ 1] : MAXD;   // pair partner
            int mx = ec > ecn ? ec : ecn;
            int pe8 = (mx + 7) & ~7;
            if (pe8 > MAXD) pe8 = MAXD;
            for (int k = ec; k < pe8; ++k)
                ell[(size_t)g * MAXD + k] = SENT;                // pad to pair-max x8
        }
    }
    __syncthreads();
    // fused vinit: convert this bucket's x rows (contiguous) to fp16 v-space
    int nrows = N_NODES - base;
    if (nrows > BKT_NODES) nrows = BKT_NODES;
    for (int i = t; i < nrows * 16; i += 256) {        // 16 float4 per row
        int r = i >> 4, q = i & 15;
        size_t g = (size_t)(base + r);
        float dv = sdinv[r];
        float4 v = ((const float4*)x)[g * 16 + q];
        __half2* o = (__half2*)(xh + g * DIM + q * 4);
        o[0] = __floats2half2_rn(dv * v.x, dv * v.y);
        o[1] = __floats2half2_rn(dv * v.z, dv * v.w);
    }
}

// Paired hop: one wave = nodes (2w, 2w+1); half-wave per node; lane handles
// 2 dims via __half2. Branch-free (pair-padded ELL). Packed fp16 chunk
// partials folded into fp32 master acc. Writes fp16 dn^2*acc (v-space).
__global__ __launch_bounds__(256) void hop_kernel(const __half* __restrict__ vin,
                                                  const int* __restrict__ ellcnt,
                                                  const int* __restrict__ ell,
                                                  const float* __restrict__ dinv,
                                                  const int2* __restrict__ ovf,
                                                  const int* __restrict__ ovf_cnt,
                                                  __half* __restrict__ y) {
    int t = blockIdx.x * blockDim.x + threadIdx.x;
    int lane = t & 63;
    int l5 = lane & 31;
    int n = ((t >> 6) << 1) + (lane >> 5);     // pair (2w, 2w+1)
    if (n >= N_NODES) return;
    int deg8 = (ellcnt[n] + 7) & ~7;           // per-half uniform
    int dther = __shfl_xor(deg8, 32, 64);
    int dmax = deg8 > dther ? deg8 : dther;    // wave-uniform (pair-padded ELL)
    int idx = ell[(n << 5) + l5];              // contiguous 256B across wave
    float dn = dinv[n];
    const __half2* v2 = (const __half2*)vin;
    float2 sf = __half22float2(v2[(size_t)(n << 5) + l5]);   // self-loop term
    float accx = sf.x, accy = sf.y;
    int orv = lane & 32;
    const __half2 hz = __floats2half2_rn(0.f, 0.f);
    for (int j = 0; j < dmax; j += 8) {
        __half2 p = hz;                        // packed fp16 chunk partial
#pragma unroll
        for (int kk = 0; kk < 8; ++kk) {
            int s = __shfl(idx, (j + kk) | orv, 64);   // own half's index
            p = __hadd2(p, v2[(size_t)(s << 5) + l5]); // v_pk_add_f16
        }
        float2 pf = __half22float2(p);
        accx += pf.x;
        accy += pf.y;
    }
    int m = *ovf_cnt;                          // expected 0
    if (m > OVF_CAP) m = OVF_CAP;
    for (int i = 0; i < m; ++i) {
        int2 e = ovf[i];
        if (e.y == n) {
            float2 gf = __half22float2(v2[(size_t)(e.x << 5) + l5]);
            accx += gf.x; accy += gf.y;
        }
    }
    float scale = dn * dn;
    ((__half2*)y)[(size_t)(n << 5) + l5] = __floats2half2_rn(scale * accx, scale * accy);
}

// Fused hop3 + linear. Block owns rows [64b, 64b+64): each wave computes
// hop3 (paired, from fully-written bufHA) for 16 of those rows, writing
// fp32 dn*acc straight into the swizzled LDS tile (no global round-trip,
// no sync needed: output rows depend only on bufHA). Then the proven
// linear: lane = row, wave = 16 cols, scalar-pipe W s_loads, coalesced IO.
__global__ __launch_bounds__(256) void hop_linear(const __half* __restrict__ vin,
                                                  const int* __restrict__ ellcnt,
                                                  const int* __restrict__ ell,
                                                  const float* __restrict__ dinv,
                                                  const int2* __restrict__ ovf,
                                                  const int* __restrict__ ovf_cnt,
                                                  const float* __restrict__ W,
                                                  float* __restrict__ out) {
    __shared__ float sx[LROWS * DIM];          // 16 KB
    int tid = threadIdx.x;
    int lane = tid & 63;
    int l5 = lane & 31;
    int w = tid >> 6;
    size_t row0 = (size_t)blockIdx.x * LROWS;
    const __half2* v2 = (const __half2*)vin;
    int m = *ovf_cnt;                          // expected 0
    if (m > OVF_CAP) m = OVF_CAP;
    const __half2 hz = __floats2half2_rn(0.f, 0.f);

    // ---- hop3 into LDS: wave w covers local rows [16w, 16w+16) as 8 pairs
    for (int p = 0; p < 8; ++p) {
        int r = w * 16 + p * 2 + (lane >> 5);  // local row 0..63
        int n = (int)row0 + r;
        if (n >= N_NODES) n = N_NODES - 1;     // clamp: redundant compute, store masked
        int deg8 = (ellcnt[n] + 7) & ~7;
        int dther = __shfl_xor(deg8, 32, 64);
        int dmax = deg8 > dther ? deg8 : dther;
        int idx = ell[(n << 5) + l5];
        float dn = dinv[n];
        float2 sf = __half22float2(v2[(size_t)(n << 5) + l5]);
        float accx = sf.x, accy = sf.y;
        int orv = lane & 32;
        for (int j = 0; j < dmax; j += 8) {
            __half2 pk = hz;
#pragma unroll
            for (int kk = 0; kk < 8; ++kk) {
                int s = __shfl(idx, (j + kk) | orv, 64);
                pk = __hadd2(pk, v2[(size_t)(s << 5) + l5]);
            }
            float2 pf = __half22float2(pk);
            accx += pf.x;
            accy += pf.y;
        }
        for (int i = 0; i < m; ++i) {
            int2 e = ovf[i];
            if (e.y == n) {
                float2 gf = __half22float2(v2[(size_t)(e.x << 5) + l5]);
                accx += gf.x; accy += gf.y;
            }
        }
        // fp32 pair into swizzled sx (chunk granularity matches linear reads)
        int chunk = l5 >> 1;
        int pos = (chunk ^ (r & 7)) * 4 + (l5 & 1) * 2;
        sx[r * DIM + pos]     = dn * accx;
        sx[r * DIM + pos + 1] = dn * accy;
    }
    __syncthreads();

    // ---- linear: out = sx @ W^T
    int wv = __builtin_amdgcn_readfirstlane(tid >> 6);   // prove wave-uniform
    float4 xr[16];
#pragma unroll
    for (int kc = 0; kc < 16; ++kc) {
        int kcs = kc ^ (lane & 7);
        xr[kc] = *(const float4*)&sx[lane * DIM + kcs * 4];
    }

    float a[4][4];
#pragma unroll
    for (int cc = 0; cc < 4; ++cc)
#pragma unroll
        for (int jj = 0; jj < 4; ++jj) a[cc][jj] = 0.f;

    int c0base = wv * 16;
#pragma unroll
    for (int cc = 0; cc < 4; ++cc) {
        int c0 = c0base + cc * 4;
        const float* __restrict__ w0 = W + (size_t)(c0 + 0) * DIM;
        const float* __restrict__ w1 = W + (size_t)(c0 + 1) * DIM;
        const float* __restrict__ w2 = W + (size_t)(c0 + 2) * DIM;
        const float* __restrict__ w3 = W + (size_t)(c0 + 3) * DIM;
#pragma unroll
        for (int q = 0; q < 16; ++q) {
            float xk[4] = {xr[q].x, xr[q].y, xr[q].z, xr[q].w};
#pragma unroll
            for (int u = 0; u < 4; ++u) {
                int k = q * 4 + u;
                a[cc][0] = fmaf(xk[u], w0[k], a[cc][0]);  // v_fmac v, s, v
                a[cc][1] = fmaf(xk[u], w1[k], a[cc][1]);
                a[cc][2] = fmaf(xk[u], w2[k], a[cc][2]);
                a[cc][3] = fmaf(xk[u], w3[k], a[cc][3]);
            }
        }
    }

    __syncthreads();                           // reuse sx for output transpose
#pragma unroll
    for (int cc = 0; cc < 4; ++cc) {
        int chunk = wv * 4 + cc;
        int cs = chunk ^ (lane & 7);
        *(float4*)&sx[lane * DIM + cs * 4] =
            make_float4(a[cc][0], a[cc][1], a[cc][2], a[cc][3]);
    }
    __syncthreads();
    for (int it = 0; it < 4; ++it) {           // coalesced float4 stores
        int i = tid + it * 256;
        int r = i >> 4, kc = i & 15;
        size_t gr = row0 + r;
        if (gr < N_NODES) {
            int kcs = kc ^ (r & 7);
            *(float4*)&out[gr * DIM + kc * 4] = *(const float4*)&sx[r * DIM + kcs * 4];
        }
    }
}

extern "C" void kernel_launch(void* const* d_in, const int* in_sizes, int n_in,
                              void* d_out, int out_size, void* d_ws, size_t ws_size,
                              hipStream_t stream) {
    const float* x     = (const float*)d_in[0];
    const float* W     = (const float*)d_in[1];
    const void*  edges = d_in[2];
    float* out = (float*)d_out;

    char* ws = (char*)d_ws;
    int*    flag    = (int*)(ws + 0);
    int*    ovf_cnt = (int*)(ws + 4);
    int*    cursors = (int*)(ws + 4096);       // totals only (scan output)
    int*    cnt     = (int*)(ws + 65536);      // 400 KB
    int*    ellcnt  = (int*)(ws + 465536);     // 400 KB
    float*  dinv    = (float*)(ws + 865536);   // 400 KB
    int2*   ovf     = (int2*)(ws + 1265536);   // 128 KB -> ends 1396608
    int*    ell     = (int*)(ws + 1396608);    // 12.8 MB -> ends 14196608
    __half* xh      = (__half*)(ws + 14196608);  // 12.8 MB + SENT row
    __half* bufHA   = (__half*)(ws + 27000832);  // 12.8 MB + SENT row
    __half* bufHB   = (__half*)(ws + 39804928);  // 12.8 MB + SENT row
    // buckets (6.4 MB packed) overlays bufHB's body: dead (ell_build done)
    // before hop<0> writes bufHB; SENT rows live beyond the overlay regions.
    int*    buckets = (int*)(ws + 39804928);
    int*    hist    = (int*)(ws + 52609024);   // NCHUNK*NBKT ints = 766 KB

    const int HB = ((N_NODES + 1) / 2 * 64 + 255) / 256;   // paired hop: 12500
    const int LB = (N_NODES + LROWS - 1) / LROWS;
    const int SB = (NBKT + 3) / 4;             // scan: 4 waves (buckets) / block

    hist_kernel<<<NCHUNK, 256, 0, stream>>>(edges, flag, cnt, ovf_cnt, hist, xh, bufHA, bufHB);
    scan_kernel<<<SB, 256, 0, stream>>>(hist, cursors);
    scatter2<<<NCHUNK, 256, 0, stream>>>(edges, flag, hist, cnt, buckets, ovf, ovf_cnt);
    ell_build<<<NBKT, 256, 0, stream>>>(cursors, cnt, ellcnt, dinv, buckets, ell,
                                        ovf, ovf_cnt, x, xh);

    // hop1: xh -> bufHB ; hop2: bufHB -> bufHA ; hop3+linear: bufHA -> out
    hop_kernel<<<HB, 256, 0, stream>>>(xh,    ellcnt, ell, dinv, ovf, ovf_cnt, bufHB);
    hop_kernel<<<HB, 256, 0, stream>>>(bufHB, ellcnt, ell, dinv, ovf, ovf_cnt, bufHA);
    hop_linear<<<LB, 256, 0, stream>>>(bufHA, ellcnt, ell, dinv, ovf, ovf_cnt, W, out);
}

// Round 20
// 136.926 us; speedup vs baseline: 1.0161x; 1.0161x over previous
//
#include <hip/hip_runtime.h>
#include <hip/hip_fp16.h>
#include <stdint.h>

#define N_NODES 100000
#define N_EDGES 1000000
#define DIM 64
#define MAXD 32                  // ELL width: 128B index row per node
#define SENT N_NODES             // sentinel -> zero row in v-buffers
#define BKT_SHIFT 7
#define BKT_NODES 128            // nodes per bucket
#define NBKT ((N_NODES + BKT_NODES - 1) / BKT_NODES)   // 782
#define BKT_CAP 2048             // >>20 sigma above mean 1279 edges/bucket
#define OVF_CAP 16384
#define CHUNK 4096               // edges per scatter block (245 blocks)
#define NCHUNK ((N_EDGES + CHUNK - 1) / CHUNK)
#define CURS_STRIDE 16
#define LROWS 64                 // linear: rows per block

__device__ __forceinline__ int load_src(const void* edges, int is64, int e) {
    if (is64) return ((const int2*)edges)[e].x;            // int64 values < 2^31
    return ((const int*)edges)[e];
}
__device__ __forceinline__ int load_dst(const void* edges, int is64, int e) {
    if (is64) return ((const int2*)edges)[N_EDGES + e].x;
    return ((const int*)edges)[N_EDGES + e];
}
__device__ __forceinline__ int detect64(const void* edges) {
    const long long* e64 = (const long long*)edges;
    int is64 = 1;
#pragma unroll
    for (int k = 0; k < 8; ++k) {
        long long v = e64[k];
        if (v < 0 || v >= (long long)N_NODES) is64 = 0;
    }
    return is64;
}

// pass A: per-block bucket histogram -> hist[blk][b]. Also zeroes cnt/ovf_cnt,
// publishes flag, and zeroes the SENT rows of the three v-buffers (block 0).
__global__ __launch_bounds__(256) void hist_kernel(const void* __restrict__ edges,
                                                   int* __restrict__ flag,
                                                   int* __restrict__ cnt,
                                                   int* __restrict__ ovf_cnt,
                                                   int* __restrict__ hist,
                                                   __half* __restrict__ xh,
                                                   __half* __restrict__ bA,
                                                   __half* __restrict__ bB) {
    __shared__ int lcnt[NBKT];
    int t = threadIdx.x;
    int is64 = detect64(edges);                 // block-local, identical result
    if (blockIdx.x == 0) {
        if (t == 0) { *flag = is64; *ovf_cnt = 0; }
        if (t < 96) {                           // zero SENT rows (3 bufs x 32 half2)
            int r = t >> 5, c = t & 31;
            __half* bufs[3] = {xh, bA, bB};
            ((__half2*)(bufs[r] + (size_t)SENT * DIM))[c] = __floats2half2_rn(0.f, 0.f);
        }
    }
    for (int i = blockIdx.x * 256 + t; i < N_NODES; i += NCHUNK * 256)
        cnt[i] = 0;
    int e0 = blockIdx.x * CHUNK;
    int e1 = min(e0 + CHUNK, N_EDGES);
    for (int i = t; i < NBKT; i += 256) lcnt[i] = 0;
    __syncthreads();
    for (int e = e0 + t; e < e1; e += 256)
        atomicAdd(&lcnt[load_dst(edges, is64, e) >> BKT_SHIFT], 1);
    __syncthreads();
    int* row = hist + (size_t)blockIdx.x * NBKT;
    for (int i = t; i < NBKT; i += 256) row[i] = lcnt[i];   // coalesced
}

// pass B: one wave per bucket: exclusive prefix over NCHUNK blocks, in place.
__global__ __launch_bounds__(256) void scan_kernel(int* __restrict__ hist,
                                                   int* __restrict__ cursors) {
    int b = blockIdx.x * 4 + (threadIdx.x >> 6);
    if (b >= NBKT) return;
    int lane = threadIdx.x & 63;
    int carry = 0;
    for (int r0 = 0; r0 < NCHUNK; r0 += 64) {
        int r = r0 + lane;
        int v = (r < NCHUNK) ? hist[(size_t)r * NBKT + b] : 0;
        int incl = v;
#pragma unroll
        for (int off = 1; off < 64; off <<= 1) {
            int u = __shfl_up(incl, off, 64);
            if (lane >= off) incl += u;
        }
        if (r < NCHUNK) hist[(size_t)r * NBKT + b] = incl - v + carry;  // exclusive
        carry += __shfl(incl, 63, 64);
    }
    if (lane == 0) cursors[b * CURS_STRIDE] = carry;        // total count
}

// pass C: scatter with LDS cursors only (no global atomics).
__global__ __launch_bounds__(256) void scatter2(const void* __restrict__ edges,
                                                const int* __restrict__ flag,
                                                const int* __restrict__ hist,
                                                int* __restrict__ cnt,
                                                int* __restrict__ buckets,
                                                int2* __restrict__ ovf,
                                                int* __restrict__ ovf_cnt) {
    __shared__ int lbase[NBKT];
    __shared__ int lcur[NBKT];
    int t = threadIdx.x;
    int e0 = blockIdx.x * CHUNK;
    int e1 = min(e0 + CHUNK, N_EDGES);
    int is64 = *flag;
    const int* row = hist + (size_t)blockIdx.x * NBKT;
    for (int i = t; i < NBKT; i += 256) { lbase[i] = row[i]; lcur[i] = 0; }
    __syncthreads();
    for (int e = e0 + t; e < e1; e += 256) {
        int s = load_src(edges, is64, e);
        int d = load_dst(edges, is64, e);
        int b = d >> BKT_SHIFT;
        int pos = lbase[b] + atomicAdd(&lcur[b], 1);        // global pos in bucket
        if (pos < BKT_CAP) {
            buckets[(size_t)b * BKT_CAP + pos] = s | ((d & (BKT_NODES - 1)) << 17);
        } else {                                            // astronomically rare
            atomicAdd(&cnt[d], 1);
            int o = atomicAdd(ovf_cnt, 1);
            if (o < OVF_CAP) ovf[o] = make_int2(s, d);
        }
    }
}

// per-bucket ELL build + fused vinit: LDS degree counters -> cnt/ellcnt/dinv,
// pair-max SENT padding, then this block converts ITS OWN 128 x-rows to fp16
// v-space (xh = fp16(dinv*x)).
__global__ __launch_bounds__(256) void ell_build(const int* __restrict__ cursors,
                                                 int* __restrict__ cnt,
                                                 int* __restrict__ ellcnt,
                                                 float* __restrict__ dinv,
                                                 const int* __restrict__ buckets,
                                                 int* __restrict__ ell,
                                                 int2* __restrict__ ovf,
                                                 int* __restrict__ ovf_cnt,
                                                 const float* __restrict__ x,
                                                 __half* __restrict__ xh) {
    __shared__ int lcnt[BKT_NODES];
    __shared__ float sdinv[BKT_NODES];
    int b = blockIdx.x, t = threadIdx.x;
    if (t < BKT_NODES) lcnt[t] = 0;
    __syncthreads();
    int m = cursors[b * CURS_STRIDE];
    if (m > BKT_CAP) m = BKT_CAP;
    int base = b * BKT_NODES;
    const int* be = buckets + (size_t)b * BKT_CAP;
    for (int i = t; i < m; i += 256) {
        int pe = be[i];
        int s = pe & 0x1FFFF;
        int off = pe >> 17;
        int k = atomicAdd(&lcnt[off], 1);
        if (k < MAXD) ell[(size_t)(base + off) * MAXD + k] = s;
        else {
            int o = atomicAdd(ovf_cnt, 1);
            if (o < OVF_CAP) ovf[o] = make_int2(s, base + off);
        }
    }
    __syncthreads();
    if (t < BKT_NODES) {
        int g = base + t;
        if (g < N_NODES) {
            int tot = cnt[g] + lcnt[t];
            cnt[g] = tot;
            int ec = lcnt[t] < MAXD ? lcnt[t] : MAXD;
            ellcnt[g] = ec;
            float dv = rsqrtf((float)(tot + 1));
            dinv[g] = dv;
            sdinv[t] = dv;
            int ecn = lcnt[t ^ 1] < MAXD ? lcnt[t ^ 1] : MAXD;   // pair partner
            int mx = ec > ecn ? ec : ecn;
            int pe8 = (mx + 7) & ~7;
            if (pe8 > MAXD) pe8 = MAXD;
            for (int k = ec; k < pe8; ++k)
                ell[(size_t)g * MAXD + k] = SENT;                // pad to pair-max x8
        }
    }
    __syncthreads();
    // fused vinit: convert this bucket's x rows (contiguous) to fp16 v-space
    int nrows = N_NODES - base;
    if (nrows > BKT_NODES) nrows = BKT_NODES;
    for (int i = t; i < nrows * 16; i += 256) {        // 16 float4 per row
        int r = i >> 4, q = i & 15;
        size_t g = (size_t)(base + r);
        float dv = sdinv[r];
        float4 v = ((const float4*)x)[g * 16 + q];
        __half2* o = (__half2*)(xh + g * DIM + q * 4);
        o[0] = __floats2half2_rn(dv * v.x, dv * v.y);
        o[1] = __floats2half2_rn(dv * v.z, dv * v.w);
    }
}

// Paired hop: one wave = nodes (2w, 2w+1); half-wave per node; lane handles
// 2 dims via __half2. Branch-free (pair-padded ELL). Packed fp16 chunk
// partials folded into fp32 master acc.
// FINAL: scale dn (x-space) else dn^2 (v-space).
template <int FINAL>
__global__ __launch_bounds__(256) void hop_kernel(const __half* __restrict__ vin,
                                                  const int* __restrict__ ellcnt,
                                                  const int* __restrict__ ell,
                                                  const float* __restrict__ dinv,
                                                  const int2* __restrict__ ovf,
                                                  const int* __restrict__ ovf_cnt,
                                                  __half* __restrict__ y) {
    int t = blockIdx.x * blockDim.x + threadIdx.x;
    int lane = t & 63;
    int l5 = lane & 31;
    int n = ((t >> 6) << 1) + (lane >> 5);     // pair (2w, 2w+1)
    if (n >= N_NODES) return;
    int deg8 = (ellcnt[n] + 7) & ~7;           // per-half uniform
    int dther = __shfl_xor(deg8, 32, 64);
    int dmax = deg8 > dther ? deg8 : dther;    // wave-uniform (pair-padded ELL)
    int idx = ell[(n << 5) + l5];              // contiguous 256B across wave
    float dn = dinv[n];
    const __half2* v2 = (const __half2*)vin;
    float2 sf = __half22float2(v2[(size_t)(n << 5) + l5]);   // self-loop term
    float accx = sf.x, accy = sf.y;
    int orv = lane & 32;
    const __half2 hz = __floats2half2_rn(0.f, 0.f);
    for (int j = 0; j < dmax; j += 8) {
        __half2 p = hz;                        // packed fp16 chunk partial
#pragma unroll
        for (int kk = 0; kk < 8; ++kk) {
            int s = __shfl(idx, (j + kk) | orv, 64);   // own half's index
            p = __hadd2(p, v2[(size_t)(s << 5) + l5]); // v_pk_add_f16
        }
        float2 pf = __half22float2(p);
        accx += pf.x;
        accy += pf.y;
    }
    int m = *ovf_cnt;                          // expected 0
    if (m > OVF_CAP) m = OVF_CAP;
    for (int i = 0; i < m; ++i) {
        int2 e = ovf[i];
        if (e.y == n) {
            float2 gf = __half22float2(v2[(size_t)(e.x << 5) + l5]);
            accx += gf.x; accy += gf.y;
        }
    }
    float scale = FINAL ? dn : dn * dn;
    ((__half2*)y)[(size_t)(n << 5) + l5] = __floats2half2_rn(scale * accx, scale * accy);
}

// out = x @ W^T, x in fp16. 4 waves / 64 rows; lane = row, wave = 16 cols
// (readfirstlane -> scalar-pipe W s_loads). XOR-swizzled LDS; coalesced IO.
__global__ __launch_bounds__(256) void linear_kernel(const __half* __restrict__ xin,
                                                     const float* __restrict__ W,
                                                     float* __restrict__ out) {
    __shared__ float sx[LROWS * DIM];          // 16 KB
    int tid = threadIdx.x;
    size_t row0 = (size_t)blockIdx.x * LROWS;

    for (int it = 0; it < 4; ++it) {
        int i = tid + it * 256;
        int r = i >> 4, kc = i & 15;
        size_t gr = row0 + r;
        if (gr >= N_NODES) gr = N_NODES - 1;   // clamp (masked at final store)
        const __half2* hp = (const __half2*)&xin[gr * DIM + kc * 4];
        float2 f0 = __half22float2(hp[0]);
        float2 f1 = __half22float2(hp[1]);
        int kcs = kc ^ (r & 7);
        *(float4*)&sx[r * DIM + kcs * 4] = make_float4(f0.x, f0.y, f1.x, f1.y);
    }
    __syncthreads();

    int lane = tid & 63;
    int wv = __builtin_amdgcn_readfirstlane(tid >> 6);   // prove wave-uniform
    float4 xr[16];
#pragma unroll
    for (int kc = 0; kc < 16; ++kc) {
        int kcs = kc ^ (lane & 7);
        xr[kc] = *(const float4*)&sx[lane * DIM + kcs * 4];
    }

    float a[4][4];
#pragma unroll
    for (int cc = 0; cc < 4; ++cc)
#pragma unroll
        for (int jj = 0; jj < 4; ++jj) a[cc][jj] = 0.f;

    int c0base = wv * 16;
#pragma unroll
    for (int cc = 0; cc < 4; ++cc) {
        int c0 = c0base + cc * 4;
        const float* __restrict__ w0 = W + (size_t)(c0 + 0) * DIM;
        const float* __restrict__ w1 = W + (size_t)(c0 + 1) * DIM;
        const float* __restrict__ w2 = W + (size_t)(c0 + 2) * DIM;
        const float* __restrict__ w3 = W + (size_t)(c0 + 3) * DIM;
#pragma unroll
        for (int q = 0; q < 16; ++q) {
            float xk[4] = {xr[q].x, xr[q].y, xr[q].z, xr[q].w};
#pragma unroll
            for (int u = 0; u < 4; ++u) {
                int k = q * 4 + u;
                a[cc][0] = fmaf(xk[u], w0[k], a[cc][0]);  // v_fmac v, s, v
                a[cc][1] = fmaf(xk[u], w1[k], a[cc][1]);
                a[cc][2] = fmaf(xk[u], w2[k], a[cc][2]);
                a[cc][3] = fmaf(xk[u], w3[k], a[cc][3]);
            }
        }
    }

    __syncthreads();                           // reuse sx for output transpose
#pragma unroll
    for (int cc = 0; cc < 4; ++cc) {
        int chunk = wv * 4 + cc;
        int cs = chunk ^ (lane & 7);
        *(float4*)&sx[lane * DIM + cs * 4] =
            make_float4(a[cc][0], a[cc][1], a[cc][2], a[cc][3]);
    }
    __syncthreads();
    for (int it = 0; it < 4; ++it) {           // coalesced float4 stores
        int i = tid + it * 256;
        int r = i >> 4, kc = i & 15;
        size_t gr = row0 + r;
        if (gr < N_NODES) {
            int kcs = kc ^ (r & 7);
            *(float4*)&out[gr * DIM + kc * 4] = *(const float4*)&sx[r * DIM + kcs * 4];
        }
    }
}

extern "C" void kernel_launch(void* const* d_in, const int* in_sizes, int n_in,
                              void* d_out, int out_size, void* d_ws, size_t ws_size,
                              hipStream_t stream) {
    const float* x     = (const float*)d_in[0];
    const float* W     = (const float*)d_in[1];
    const void*  edges = d_in[2];
    float* out = (float*)d_out;

    char* ws = (char*)d_ws;
    int*    flag    = (int*)(ws + 0);
    int*    ovf_cnt = (int*)(ws + 4);
    int*    cursors = (int*)(ws + 4096);       // totals only (scan output)
    int*    cnt     = (int*)(ws + 65536);      // 400 KB
    int*    ellcnt  = (int*)(ws + 465536);     // 400 KB
    float*  dinv    = (float*)(ws + 865536);   // 400 KB
    int2*   ovf     = (int2*)(ws + 1265536);   // 128 KB -> ends 1396608
    int*    ell     = (int*)(ws + 1396608);    // 12.8 MB -> ends 14196608
    __half* xh      = (__half*)(ws + 14196608);  // 12.8 MB + SENT row
    __half* bufHA   = (__half*)(ws + 27000832);  // 12.8 MB + SENT row
    __half* bufHB   = (__half*)(ws + 39804928);  // 12.8 MB + SENT row
    // buckets (6.4 MB packed) overlays bufHB's body: dead (ell_build done)
    // before hop<0> writes bufHB; SENT rows live beyond the overlay regions.
    int*    buckets = (int*)(ws + 39804928);
    int*    hist    = (int*)(ws + 52609024);   // NCHUNK*NBKT ints = 766 KB

    const int HB = ((N_NODES + 1) / 2 * 64 + 255) / 256;   // paired hop: 12500
    const int LB = (N_NODES + LROWS - 1) / LROWS;
    const int SB = (NBKT + 3) / 4;             // scan: 4 waves (buckets) / block

    hist_kernel<<<NCHUNK, 256, 0, stream>>>(edges, flag, cnt, ovf_cnt, hist, xh, bufHA, bufHB);
    scan_kernel<<<SB, 256, 0, stream>>>(hist, cursors);
    scatter2<<<NCHUNK, 256, 0, stream>>>(edges, flag, hist, cnt, buckets, ovf, ovf_cnt);
    ell_build<<<NBKT, 256, 0, stream>>>(cursors, cnt, ellcnt, dinv, buckets, ell,
                                        ovf, ovf_cnt, x, xh);

    // hop1: xh -> bufHB ; hop2: bufHB -> bufHA ; hop3(final): bufHA -> bufHB
    hop_kernel<0><<<HB, 256, 0, stream>>>(xh,    ellcnt, ell, dinv, ovf, ovf_cnt, bufHB);
    hop_kernel<0><<<HB, 256, 0, stream>>>(bufHB, ellcnt, ell, dinv, ovf, ovf_cnt, bufHA);
    hop_kernel<1><<<HB, 256, 0, stream>>>(bufHA, ellcnt, ell, dinv, ovf, ovf_cnt, bufHB);

    linear_kernel<<<LB, 256, 0, stream>>>(bufHB, W, out);
}